// Round 11
// baseline (160.281 us; speedup 1.0000x reference)
//
#include <hip/hip_runtime.h>
#include <stdint.h>

#define B_   2
#define C_   256
#define N_   4096
#define TD_  512
#define OC_  128   // C/2
#define PW_  66    // padded width/height
#define PA_  4356  // 66*66

typedef float  f32x4  __attribute__((ext_vector_type(4)));
typedef short  bf16x8 __attribute__((ext_vector_type(8)));
typedef unsigned short u16;
typedef unsigned char  u8;

__device__ __forceinline__ u16 f2bf(float x){
  union { float f; uint32_t u; } v; v.f = x;
  uint32_t r = v.u + 0x7fffu + ((v.u >> 16) & 1u);
  return (u16)(r >> 16);
}
// f32 -> e5m2 byte (clamped, RNE via f16 high-byte truncation)
__device__ __forceinline__ uint32_t f2e5m2(float x){
  x = fminf(fmaxf(x, -57344.f), 57344.f);
  union { _Float16 h; u16 u; } c; c.h = (_Float16)x;
  uint32_t hb = c.u;
  return ((hb + 0x7fu + ((hb >> 8) & 1u)) >> 8) & 0xffu;
}
__device__ __forceinline__ float e5m2f(uint32_t byte){
  union { u16 u; _Float16 h; } c; c.u = (u16)(byte << 8);
  return (float)c.h;
}

__device__ __forceinline__ void gld_lds16(const void* g, void* l){
  __builtin_amdgcn_global_load_lds(
      (const __attribute__((address_space(1))) unsigned int*)g,
      (__attribute__((address_space(3))) unsigned int*)l,
      16, 0, 0);
}

// ------- K1: prep (1024 thr/blk) = FiLM (0-1) + qinit (2-3) + repack (4..291) + Pzero (292..308)
__global__ __launch_bounds__(1024) void k_prep(
    const float* __restrict__ txt, const float* __restrict__ Wt, const float* __restrict__ bt,
    const float* __restrict__ Wg, const float* __restrict__ bg,
    const float* __restrict__ Wb, const float* __restrict__ bb,
    const float* __restrict__ dens, const float* __restrict__ Wo, const float* __restrict__ Wc1,
    float* __restrict__ gamma, float* __restrict__ beta,
    float* __restrict__ q, float* __restrict__ u,
    u16* __restrict__ Wo_bf, u16* __restrict__ Wc1r, u16* __restrict__ P){
  int bid = blockIdx.x;
  int t = threadIdx.x;
  if (bid < 2){                                   // ---- FiLM, 16-wave TLP, float4 loads
    int b = bid;
    __shared__ float ts[TD_];
    __shared__ float te[C_];
    if (t < TD_) ts[t] = txt[b*TD_ + t];
    __syncthreads();
    {
      int c = t >> 2, p = t & 3;                  // 4 threads per output
      const float4* w4 = (const float4*)(Wt + (size_t)c*TD_ + p*128);
      const float4* t4 = (const float4*)(ts + p*128);
      float a = 0.f;
      #pragma unroll 8
      for (int j = 0; j < 32; j++){
        float4 wv = w4[j], tv = t4[j];
        a += wv.x*tv.x + wv.y*tv.y + wv.z*tv.z + wv.w*tv.w;
      }
      a += __shfl_xor(a, 1);
      a += __shfl_xor(a, 2);
      if (p == 0) te[c] = a + bt[c];
    }
    __syncthreads();
    {
      int c = t >> 2, qb = (t >> 1) & 1, p = t & 1;   // (output, gamma/beta, half)
      const float* W = qb ? Wb : Wg;
      const float4* w4 = (const float4*)(W + (size_t)c*C_ + p*128);
      const float4* t4 = (const float4*)(te + p*128);
      float a = 0.f;
      #pragma unroll 8
      for (int j = 0; j < 32; j++){
        float4 wv = w4[j], tv = t4[j];
        a += wv.x*tv.x + wv.y*tv.y + wv.z*tv.z + wv.w*tv.w;
      }
      a += __shfl_xor(a, 1);
      if (p == 0){
        if (qb) beta[b*C_ + c]  = a + bb[c];
        else    gamma[b*C_ + c] = a + bg[c];
      }
    }
  } else if (bid < 4){                            // ---- qinit
    int b = bid - 2;
    __shared__ float red[1024];
    float s = 0.f;
    for (int i = t; i < N_; i += 1024){ float v = fmaxf(dens[b*N_ + i], 0.f) + 1e-6f; s += v; }
    red[t] = s; __syncthreads();
    for (int o = 512; o; o >>= 1){ if (t < o) red[t] += red[t + o]; __syncthreads(); }
    float invs = 1.f / red[0];
    for (int i = t; i < N_; i += 1024){
      float v = fmaxf(dens[b*N_ + i], 0.f) + 1e-6f;
      q[b*N_ + i] = v*invs;
      u[b*N_ + i] = 1.f;
    }
  } else if (bid < 292){                          // ---- repack (288 blocks x 1024 = 294912)
    int i = (bid - 4)*1024 + t;
    if (i < C_*C_) Wo_bf[i] = f2bf(Wo[i]);
    if (i < 9*OC_*C_){
      int s = i / (OC_*C_); int rem = i - s*(OC_*C_);
      int oc = rem >> 8; int ic = rem & 255;
      Wc1r[i] = f2bf(Wc1[((size_t)(oc*C_ + ic))*9 + s]);
    }
  } else {                                        // ---- P border zero (16640 uint4 total)
    int g = (bid - 292)*1024 + t;
    if (g < 16640){
      int px_i = g >> 5, seg = g & 31;
      int b = (px_i >= 260) ? 1 : 0;
      int i = px_i - b*260;
      int row, col;
      if (i < 66)      { row = 0;  col = i; }
      else if (i < 132){ row = 65; col = i - 66; }
      else { int i2 = i - 132; row = 1 + (i2 >> 1); col = (i2 & 1) ? 65 : 0; }
      uint4 z; z.x = 0; z.y = 0; z.z = 0; z.w = 0;
      *(uint4*)((char*)P + ((size_t)(b*PA_ + row*PW_ + col))*512 + seg*16) = z;
    }
  }
}

// ---------------------------------------- K2: mod + L2-normalize -> Sn NHWC bf16
__global__ __launch_bounds__(256) void k_build(
    const float* __restrict__ img, const float* __restrict__ gamma, const float* __restrict__ beta,
    u16* __restrict__ Sn){
  int b = blockIdx.y; int n0 = blockIdx.x*64;
  __shared__ float tile[C_][65];
  __shared__ float pss[4][64];
  __shared__ float inv[64];
  int t = threadIdx.x;
  int x = t & 63, cb = t >> 6;
  float ss = 0.f;
  for (int k = 0; k < 64; k++){
    int c = cb*64 + k;
    float v = img[((size_t)(b*C_ + c))*N_ + n0 + x];
    v = v*(1.f + gamma[b*C_ + c]) + beta[b*C_ + c];
    tile[c][x] = v;
    ss += v*v;
  }
  pss[cb][x] = ss;
  __syncthreads();
  if (t < 64){
    float s = pss[0][t] + pss[1][t] + pss[2][t] + pss[3][t];
    float nrm = sqrtf(s);
    inv[t] = 1.f / fmaxf(nrm, 1e-12f);
  }
  __syncthreads();
  for (int i = 0; i < 64; i++){
    int idx = i*256 + t;
    int c = idx & 255, nl = idx >> 8;
    Sn[((size_t)(b*N_ + n0 + nl))*C_ + c] = f2bf(tile[c][nl]*inv[nl]);
  }
}

// ------------------------- K3: sim = Sn@Sn^T (SYMMETRIC: upper-tri pairs only),
// K8 = e5m2(exp((sim-1)/eps)); per-tile nonzero FLAG. Zero tiles: flag only, NO stores
// (downstream reads are all flag-guarded, so zero tiles are never read).
__global__ __launch_bounds__(256) void k_simK(const u16* __restrict__ Sn, u8* __restrict__ K8,
                                              u8* __restrict__ flags){
  int idx = blockIdx.x;            // 0..527 upper-triangular pair index
  int b = blockIdx.z;
  int nt = (int)((sqrtf(8.f*idx + 1.f) - 1.f)*0.5f);
  while ((nt+1)*(nt+2)/2 <= idx) nt++;
  while (nt*(nt+1)/2 > idx) nt--;
  int mt = idx - nt*(nt+1)/2;      // mt <= nt
  __shared__ char smem[32768];     // As 16KB | Bs 16KB; epilogue reuses first 16KB
  __shared__ int fred[4];
  int t = threadIdx.x; int w = t >> 6; int l = t & 63;
  int wm = w >> 1, wn = w & 1;
  f32x4 acc[4][4] = {};
  const char* Ab = (const char*)(Sn + ((size_t)(b*N_ + mt*128))*C_);
  const char* Bb = (const char*)(Sn + ((size_t)(b*N_ + nt*128))*C_);
  for (int step = 0; step < 4; step++){
    __syncthreads();
    for (int r = 0; r < 4; r++){
      int off = r*4096 + t*16;
      int row = off >> 7;
      int col = (off & 127) ^ ((row & 7) << 4);   // inverse-swizzled source
      gld_lds16(Ab + (size_t)row*512 + step*128 + col, smem + off);
      gld_lds16(Bb + (size_t)row*512 + step*128 + col, smem + 16384 + off);
    }
    __syncthreads();
    for (int kk = 0; kk < 2; kk++){
      bf16x8 af[4], bfv[4];
      for (int i = 0; i < 4; i++){
        int ra = wm*64 + i*16 + (l & 15);
        af[i]  = *(const bf16x8*)(smem + ((ra*128 + kk*64 + (l>>4)*16) ^ ((ra & 7) << 4)));
        int rb = wn*64 + i*16 + (l & 15);
        bfv[i] = *(const bf16x8*)(smem + 16384 + ((rb*128 + kk*64 + (l>>4)*16) ^ ((rb & 7) << 4)));
      }
      for (int i = 0; i < 4; i++)
        for (int j = 0; j < 4; j++)
          acc[i][j] = __builtin_amdgcn_mfma_f32_16x16x32_bf16(af[i], bfv[j], acc[i][j], 0, 0, 0);
    }
  }
  // ---- tile nonzero flag (conservative: sim > 0.40 anywhere; e5m2 cutoff is 0.411)
  float tmax = -1.f;
  for (int i = 0; i < 4; i++)
    for (int j = 0; j < 4; j++){
      f32x4 a = acc[i][j];
      tmax = fmaxf(tmax, fmaxf(fmaxf(a[0], a[1]), fmaxf(a[2], a[3])));
    }
  int nz = __any(tmax > 0.40f) ? 1 : 0;
  if (l == 0) fred[w] = nz;
  __syncthreads();                 // also guarantees all MFMA LDS reads done
  int F = fred[0] | fred[1] | fred[2] | fred[3];
  if (t == 0){
    flags[b*1024 + nt*32 + mt] = (u8)F;
    if (mt != nt) flags[b*1024 + mt*32 + nt] = (u8)F;
  }
  if (!F) return;                  // zero tile: never read downstream (flag-guarded)
  size_t gb  = ((size_t)(b*N_ + nt*128))*N_ + mt*128;
  size_t gb2 = ((size_t)(b*N_ + mt*128))*N_ + nt*128;
  // epilogue 1: exp -> e5m2, tile[R=n][C=m] (swizzled), save packed words
  u8* tile = (u8*)smem;
  uint32_t wds[4][4];
  for (int i = 0; i < 4; i++)
    for (int j = 0; j < 4; j++){
      int R  = wn*64 + j*16 + (l & 15);          // n-side
      int Cc = wm*64 + i*16 + ((l >> 4) << 2);   // m-side (4 consecutive)
      uint32_t wd =  f2e5m2(__expf((acc[i][j][0] - 1.f)*20.f))
                  | (f2e5m2(__expf((acc[i][j][1] - 1.f)*20.f)) << 8)
                  | (f2e5m2(__expf((acc[i][j][2] - 1.f)*20.f)) << 16)
                  | (f2e5m2(__expf((acc[i][j][3] - 1.f)*20.f)) << 24);
      wds[i][j] = wd;
      *(uint32_t*)(tile + ((R*128 + Cc) ^ ((R & 7) << 4))) = wd;
    }
  __syncthreads();
  // write-out: K8[b][nt*128+R][mt*128 + 0..127]
  for (int p = 0; p < 4; p++){
    int id2 = p*256 + t;
    int R = id2 >> 3, sl = id2 & 7;
    uint4 vv = *(const uint4*)(tile + ((R*128 + sl*16) ^ ((R & 7) << 4)));
    *(uint4*)(K8 + gb + (size_t)R*N_ + sl*16) = vv;
  }
  // epilogue 2 (off-diagonal): transpose tile[R=m][C=n], write K8[mt-blk][nt-blk]
  if (mt != nt){
    __syncthreads();
    for (int i = 0; i < 4; i++)
      for (int j = 0; j < 4; j++){
        int m0 = wm*64 + i*16 + ((l >> 4) << 2);
        int n  = wn*64 + j*16 + (l & 15);
        uint32_t wd = wds[i][j];
        for (int r = 0; r < 4; r++){
          int R = m0 + r;
          tile[(R*128 + n) ^ ((R & 7) << 4)] = (u8)(wd >> (8*r));
        }
      }
    __syncthreads();
    for (int p = 0; p < 4; p++){
      int id2 = p*256 + t;
      int R = id2 >> 3, sl = id2 & 7;
      uint4 vv = *(const uint4*)(tile + ((R*128 + sl*16) ^ ((R & 7) << 4)));
      *(uint4*)(K8 + gb2 + (size_t)R*N_ + sl*16) = vv;
    }
  }
}

// ---- K4: Sinkhorn via flag-graph connected components, ONE launch.
// Owner (min tile in comp) runs all 3 iterations locally; per-pair flag guard
// (unflagged pairs are exact-zero tiles, never stored by simK).
__global__ __launch_bounds__(256) void k_sink(
    const u8* __restrict__ K8, const u8* __restrict__ flags,
    const float* __restrict__ q,
    const float* __restrict__ img, const float* __restrict__ gamma,
    const float* __restrict__ beta,
    float* __restrict__ u, float* __restrict__ v, u8* __restrict__ uS8){
  int r = blockIdx.x, b = blockIdx.y;
  int t = threadIdx.x;
  __shared__ uint32_t mask[32];
  __shared__ uint32_t comp_s;
  __shared__ u8 tl[32];
  __shared__ int scnt;
  __shared__ float xb[4096];
  __shared__ float yb[4096];
  if (t < 32){
    const u8* fr = flags + b*1024 + t*32;
    uint32_t m = 0;
    for (int j = 0; j < 32; j++) m |= (uint32_t)(fr[j] != 0) << j;
    mask[t] = m;
  }
  __syncthreads();
  if (t == 0){
    uint32_t comp = 1u << r;
    for (int it = 0; it < 32; it++){
      uint32_t nc = comp;
      for (int i = 0; i < 32; i++) if ((comp >> i) & 1u) nc |= mask[i];
      if (nc == comp) break;
      comp = nc;
    }
    comp_s = comp;
    int c = 0;
    for (int i = 0; i < 32; i++) if ((comp >> i) & 1u) tl[c++] = (u8)i;
    scnt = c;
  }
  __syncthreads();
  uint32_t comp = comp_s;
  if (comp & ((1u << r) - 1u)) return;   // block-uniform: not the owner
  int s = scnt;
  int R = s*128;
  for (int i = t; i < R; i += 256) xb[i] = 1.f;   // u0 = 1
  __syncthreads();
  for (int it = 0; it < 6; it++){
    int use_q = !(it & 1);
    for (int ri = t; ri < R; ri += 256){
      int rt = tl[ri >> 7];
      int gm = rt*128 + (ri & 127);
      const u8* kp = K8 + ((size_t)(b*N_ + gm))*N_;
      uint32_t rowmask = mask[rt];
      float ssum = 0.f;
      for (int ci = 0; ci < s; ci++){
        if (!((rowmask >> tl[ci]) & 1u)) continue;  // exact-zero tile, never stored
        const u8* kt = kp + tl[ci]*128;
        const float* xp = xb + ci*128;
        for (int kk = 0; kk < 16; kk++){
          uint2 kv = *(const uint2*)(kt + kk*8);
          const float* x8 = xp + kk*8;
          ssum += e5m2f( kv.x        & 0xff)*x8[0] + e5m2f((kv.x >>  8) & 0xff)*x8[1]
                + e5m2f((kv.x >> 16) & 0xff)*x8[2] + e5m2f( kv.x >> 24        )*x8[3];
          ssum += e5m2f( kv.y        & 0xff)*x8[4] + e5m2f((kv.y >>  8) & 0xff)*x8[5]
                + e5m2f((kv.y >> 16) & 0xff)*x8[6] + e5m2f( kv.y >> 24        )*x8[7];
        }
      }
      float marg = use_q ? q[b*N_ + gm] : 2.44140625e-4f;
      yb[ri] = marg / (ssum + 1e-8f);
    }
    __syncthreads();
    if (it == 4)
      for (int i = t; i < R; i += 256) v[b*N_ + tl[i >> 7]*128 + (i & 127)] = yb[i];
    if (it == 5)
      for (int i = t; i < R; i += 256) u[b*N_ + tl[i >> 7]*128 + (i & 127)] = yb[i];
    for (int i = t; i < R; i += 256) xb[i] = yb[i];
    __syncthreads();
  }
  // xb = final u for comp rows; emit uS8[b][c][n] for n in comp
  int qpc = R >> 2;                 // quads per channel
  int quads = C_ * qpc;
  for (int qd = t; qd < quads; qd += 256){
    int c  = qd / qpc;
    int nq = qd - c*qpc;
    int ri = nq*4;
    int n = tl[ri >> 7]*128 + (ri & 127);
    size_t bc = (size_t)(b*C_ + c);
    float gm = 1.f + gamma[bc];
    float bt = beta[bc];
    float4 vi = *(const float4*)(img + bc*N_ + n);
    uint32_t o =  f2e5m2((vi.x*gm + bt)*xb[ri+0])
               | (f2e5m2((vi.y*gm + bt)*xb[ri+1]) << 8)
               | (f2e5m2((vi.z*gm + bt)*xb[ri+2]) << 16)
               | (f2e5m2((vi.w*gm + bt)*xb[ri+3]) << 24);
    *(uint32_t*)(uS8 + bc*N_ + n) = o;
  }
}

// --------- K6: direct bf8xbf8 GEMM, full K (32 flag-guarded BK=128 steps), v-scaled bf16 out
__global__ __launch_bounds__(256) void k_fused(
    const u8* __restrict__ K8, const u8* __restrict__ uS8, const u8* __restrict__ flags,
    const float* __restrict__ vvec, u16* __restrict__ fused){
  int ct = blockIdx.x;              // 0..1 : 128-c block
  int mt = blockIdx.y, b = blockIdx.z;
  __shared__ char smem[32768];      // As [128c][128k] fp8 | Bs [128m][128k] fp8
  int t = threadIdx.x, w = t >> 6, l = t & 63;
  int wc = w >> 1, wm = w & 1;
  f32x4 acc[4][4] = {};
  const u8* Ab = uS8 + ((size_t)(b*C_ + ct*128))*N_;
  const u8* Bb = K8  + ((size_t)(b*N_ + mt*128))*N_;
  const u8* fr = flags + b*1024 + mt*32;
  for (int step = 0; step < 32; step++){
    if (!fr[step]) continue;        // all-zero K tile: exact skip (block-uniform)
    __syncthreads();
    for (int r = 0; r < 4; r++){
      int off = r*4096 + t*16;
      int row = off >> 7;
      int col = (off & 127) ^ ((row & 7) << 4);
      gld_lds16(Ab + (size_t)row*N_ + step*128 + col, smem + off);
      gld_lds16(Bb + (size_t)row*N_ + step*128 + col, smem + 16384 + off);
    }
    __syncthreads();
    for (int kk = 0; kk < 4; kk++){
      long av[4], bv[4];
      for (int i = 0; i < 4; i++){
        int ra = wc*64 + i*16 + (l & 15);
        av[i] = *(const long*)(smem + ((ra*128 + kk*32 + (l>>4)*8) ^ ((ra & 7) << 4)));
        int rb = wm*64 + i*16 + (l & 15);
        bv[i] = *(const long*)(smem + 16384 + ((rb*128 + kk*32 + (l>>4)*8) ^ ((rb & 7) << 4)));
      }
      for (int i = 0; i < 4; i++)
        for (int j = 0; j < 4; j++)
          acc[i][j] = __builtin_amdgcn_mfma_f32_16x16x32_bf8_bf8(av[i], bv[j], acc[i][j], 0, 0, 0);
    }
  }
  for (int j = 0; j < 4; j++){
    int m = mt*128 + wm*64 + j*16 + (l & 15);
    float vm = vvec[b*N_ + m];
    for (int i = 0; i < 4; i++){
      int c0 = ct*128 + wc*64 + i*16 + ((l >> 4) << 2);
      ushort4 o;
      o.x = f2bf(acc[i][j][0]*vm);
      o.y = f2bf(acc[i][j][1]*vm);
      o.z = f2bf(acc[i][j][2]*vm);
      o.w = f2bf(acc[i][j][3]*vm);
      *(ushort4*)(fused + ((size_t)(b*N_ + m))*C_ + c0) = o;
    }
  }
}

// -------- K7: out = img + Wo@fused + bo (NCHW f32) AND padded-NHWC bf16 P (LDS transpose)
__global__ __launch_bounds__(256) void k_outproj(
    const u16* __restrict__ fused, const u16* __restrict__ Wo_bf,
    const float* __restrict__ img, const float* __restrict__ bo,
    float* __restrict__ out, u16* __restrict__ P){
  int nt = blockIdx.x, ot = blockIdx.y, b = blockIdx.z;
  int t = threadIdx.x, w = t >> 6, l = t & 63;
  int wm = w >> 1, wn = w & 1;
  __shared__ u16 tile[128][72];   // [n_local][o_local], pad 72
  f32x4 acc[4][2] = {};
  for (int kc = 0; kc < 8; kc++){
    bf16x8 af[4], bfv[2];
    for (int i = 0; i < 4; i++){
      int n = nt*128 + wm*64 + i*16 + (l & 15);
      af[i] = *(const bf16x8*)(fused + ((size_t)(b*N_ + n))*C_ + kc*32 + (l >> 4)*8);
    }
    for (int j = 0; j < 2; j++){
      int o = ot*64 + wn*32 + j*16 + (l & 15);
      bfv[j] = *(const bf16x8*)(Wo_bf + (size_t)o*C_ + kc*32 + (l >> 4)*8);
    }
    for (int i = 0; i < 4; i++)
      for (int j = 0; j < 2; j++)
        acc[i][j] = __builtin_amdgcn_mfma_f32_16x16x32_bf16(af[i], bfv[j], acc[i][j], 0, 0, 0);
  }
  for (int i = 0; i < 4; i++)
    for (int j = 0; j < 2; j++){
      int ol = wn*32 + j*16 + (l & 15);
      int o = ot*64 + ol;
      int nl = wm*64 + i*16 + ((l >> 4) << 2);
      int n = nt*128 + nl;
      size_t a = ((size_t)(b*C_ + o))*N_ + n;
      float4 iv = *(const float4*)(img + a);
      float bov = bo[o];
      float4 r;
      r.x = iv.x + acc[i][j][0] + bov;
      r.y = iv.y + acc[i][j][1] + bov;
      r.z = iv.z + acc[i][j][2] + bov;
      r.w = iv.w + acc[i][j][3] + bov;
      *(float4*)(out + a) = r;
      tile[nl+0][ol] = f2bf(r.x);
      tile[nl+1][ol] = f2bf(r.y);
      tile[nl+2][ol] = f2bf(r.z);
      tile[nl+3][ol] = f2bf(r.w);
    }
  __syncthreads();
  for (int p = 0; p < 4; p++){
    int idx = p*256 + t;
    int row = idx >> 3, seg = idx & 7;
    int n = nt*128 + row;
    int y = n >> 6, x = n & 63;
    uint4 vv = *(const uint4*)(&tile[row][seg*8]);
    *(uint4*)(P + ((size_t)(b*PA_ + (y+1)*PW_ + (x+1)))*C_ + ot*64 + seg*8) = vv;
  }
}

// ---------------- K8: conv3x3 via padded-GEMM, tile 128px x 128oc, FULL K=2304 (36 steps),
// writes h (+bias) directly and folds BN partial sums into the epilogue (kills k_stats).
__global__ __launch_bounds__(256) void k_conv(
    const u16* __restrict__ P, const u16* __restrict__ Wc1r, const float* __restrict__ bc1,
    float* __restrict__ h, float* __restrict__ pSum, float* __restrict__ pSsq){
  int pt = blockIdx.x;            // 0..31 : 128 px (2 image rows)
  int b  = blockIdx.y;
  __shared__ char smem[32768];    // As(weights) 16KB | Bs(pixels) 16KB
  int t = threadIdx.x, w = t >> 6, l = t & 63;
  int wm = w >> 1, wn = w & 1;
  f32x4 acc[4][4] = {};
  int y0 = pt*2;
  size_t prowB[4], wrowB[4];
  int colsw[4];
  #pragma unroll
  for (int rr = 0; rr < 4; rr++){
    int off = rr*4096 + t*16;
    int row = off >> 7;
    int col = (off & 127) ^ ((row & 7) << 4);
    colsw[rr] = col;
    int gy = row >> 6, gx = row & 63;
    prowB[rr] = ((size_t)(b*PA_ + (y0 + gy + 1)*PW_ + gx + 1))*512;  // dy=0 base
    wrowB[rr] = (size_t)row*512;
  }
  const char* Pb = (const char*)P;
  const char* Wb = (const char*)Wc1r;
  for (int step = 0; step < 36; step++){
    int sp  = step / 12;
    int rem = step - sp*12;
    int dxi = rem >> 2, c64 = rem & 3;            // dy = sp-1, dx = dxi-1
    int s = sp*3 + dxi;
    long pShift = (long)(sp - 1)*(PW_*512) + (long)(dxi - 1)*512 + c64*128;
    size_t wShift = (size_t)s*65536 + (size_t)c64*128;
    __syncthreads();
    #pragma unroll
    for (int rr = 0; rr < 4; rr++){
      int off = rr*4096 + t*16;
      gld_lds16(Wb + wrowB[rr] + wShift + colsw[rr], smem + off);
      gld_lds16(Pb + (long)prowB[rr] + pShift + colsw[rr], smem + 16384 + off);
    }
    __syncthreads();
    for (int kk = 0; kk < 2; kk++){
      bf16x8 af[4], bv[4];
      for (int i = 0; i < 4; i++){
        int ra = wm*64 + i*16 + (l & 15);
        af[i] = *(const bf16x8*)(smem + ((ra*128 + kk*64 + (l>>4)*16) ^ ((ra & 7) << 4)));
        int rb = wn*64 + i*16 + (l & 15);
        bv[i] = *(const bf16x8*)(smem + 16384 + ((rb*128 + kk*64 + (l>>4)*16) ^ ((rb & 7) << 4)));
      }
      for (int i = 0; i < 4; i++)
        for (int j = 0; j < 4; j++)
          acc[i][j] = __builtin_amdgcn_mfma_f32_16x16x32_bf16(af[i], bv[j], acc[i][j], 0, 0, 0);
    }
  }
  // epilogue: h = acc + bias; BN partial sums (per oc over this block's 128 px)
  __syncthreads();
  float* sL = (float*)smem;            // [2][128]
  float* qL = (float*)(smem + 1024);   // [2][128]
  float sv[4][4], qv[4][4];
  #pragma unroll
  for (int i = 0; i < 4; i++)
    #pragma unroll
    for (int e = 0; e < 4; e++){ sv[i][e] = 0.f; qv[i][e] = 0.f; }
  #pragma unroll
  for (int i = 0; i < 4; i++){
    int ocl = wm*64 + i*16 + ((l >> 4) << 2);
    float4 bc = *(const float4*)(bc1 + ocl);
    #pragma unroll
    for (int j = 0; j < 4; j++){
      int pxl = wn*64 + j*16 + (l & 15);
      float4 r;
      r.x = acc[i][j][0] + bc.x;
      r.y = acc[i][j][1] + bc.y;
      r.z = acc[i][j][2] + bc.z;
      r.w = acc[i][j][3] + bc.w;
      *(float4*)(h + ((size_t)(b*N_ + pt*128 + pxl))*OC_ + ocl) = r;
      sv[i][0] += r.x;     sv[i][1] += r.y;     sv[i][2] += r.z;     sv[i][3] += r.w;
      qv[i][0] += r.x*r.x; qv[i][1] += r.y*r.y; qv[i][2] += r.z*r.z; qv[i][3] += r.w*r.w;
    }
  }
  #pragma unroll
  for (int o = 1; o < 16; o <<= 1){
    #pragma unroll
    for (int i = 0; i < 4; i++)
      #pragma unroll
      for (int e = 0; e < 4; e++){
        sv[i][e] += __shfl_xor(sv[i][e], o);
        qv[i][e] += __shfl_xor(qv[i][e], o);
      }
  }
  if ((l & 15) == 0){
    #pragma unroll
    for (int i = 0; i < 4; i++){
      int ocl = wm*64 + i*16 + ((l >> 4) << 2);
      #pragma unroll
      for (int e = 0; e < 4; e++){
        sL[wn*128 + ocl + e] = sv[i][e];
        qL[wn*128 + ocl + e] = qv[i][e];
      }
    }
  }
  __syncthreads();
  if (t < 128){
    int blk = b*32 + pt;
    pSum[blk*128 + t] = sL[t] + sL[128 + t];
    pSsq[blk*128 + t] = qL[t] + qL[128 + t];
  }
}

// ----------- K10: BN finalize (in-block) + relu(h*sc+sh) -> 1x1 conv (2ch) -> heatmap
__global__ __launch_bounds__(256) void k_head(
    const float* __restrict__ h, const float* __restrict__ pSum, const float* __restrict__ pSsq,
    const float* __restrict__ bn_g, const float* __restrict__ bn_b,
    const float* __restrict__ Wc2, const float* __restrict__ bc2, float* __restrict__ hm){
  __shared__ float sc[128], sh[128], w0[128], w1[128];
  __shared__ float rs[256], rss[256];
  int t = threadIdx.x;
  {
    int c = t & 127, half = t >> 7;
    float s = 0.f, ss = 0.f;
    for (int k = half*32; k < half*32 + 32; k++){
      s += pSum[k*128 + c]; ss += pSsq[k*128 + c];
    }
    rs[t] = s; rss[t] = ss;
  }
  __syncthreads();
  if (t < 128){
    float s = rs[t] + rs[t+128], ss = rss[t] + rss[t+128];
    float m = s*(1.f/8192.f);
    float var = ss*(1.f/8192.f) - m*m;
    float scv = bn_g[t]*rsqrtf(var + 1e-5f);
    sc[t] = scv; sh[t] = bn_b[t] - m*scv;
    w0[t] = Wc2[t]; w1[t] = Wc2[128 + t];
  }
  __syncthreads();
  int n = blockIdx.x*256 + t;          // 0..8191 = b*4096+p
  const float* hp = h + (size_t)n*OC_;
  float a0 = bc2[0], a1 = bc2[1];
  for (int c4 = 0; c4 < 32; c4++){
    float4 hv = *(const float4*)(hp + c4*4);
    int c = c4*4;
    float r;
    r = fmaxf(hv.x*sc[c]   + sh[c],   0.f); a0 += w0[c]*r;   a1 += w1[c]*r;
    r = fmaxf(hv.y*sc[c+1] + sh[c+1], 0.f); a0 += w0[c+1]*r; a1 += w1[c+1]*r;
    r = fmaxf(hv.z*sc[c+2] + sh[c+2], 0.f); a0 += w0[c+2]*r; a1 += w1[c+2]*r;
    r = fmaxf(hv.w*sc[c+3] + sh[c+3], 0.f); a0 += w0[c+3]*r; a1 += w1[c+3]*r;
  }
  int b = n >> 12, p = n & 4095;
  hm[((size_t)(b*2 + 0))*N_ + p] = a0;
  hm[((size_t)(b*2 + 1))*N_ + p] = a1;
}

// ================================================================ launcher
extern "C" void kernel_launch(void* const* d_in, const int* in_sizes, int n_in,
                              void* d_out, int out_size, void* d_ws, size_t ws_size,
                              hipStream_t stream){
  const float* img  = (const float*)d_in[0];
  const float* txt  = (const float*)d_in[1];
  const float* dens = (const float*)d_in[2];
  const float* Wt   = (const float*)d_in[3];
  const float* bt   = (const float*)d_in[4];
  const float* Wg   = (const float*)d_in[5];
  const float* bg   = (const float*)d_in[6];
  const float* Wb   = (const float*)d_in[7];
  const float* bb   = (const float*)d_in[8];
  const float* Wo   = (const float*)d_in[9];
  const float* bo   = (const float*)d_in[10];
  const float* Wc1  = (const float*)d_in[11];
  const float* bc1  = (const float*)d_in[12];
  const float* bng  = (const float*)d_in[13];
  const float* bnb  = (const float*)d_in[14];
  const float* Wc2  = (const float*)d_in[15];
  const float* bc2  = (const float*)d_in[16];

  char* ws = (char*)d_ws;
  u8*       K8     = (u8*)      (ws + 0);           // 33,554,432
  u16*      Sn     = (u16*)     (ws + 33554432);    //  4,194,304
  u8*       uS8    = (u8*)      (ws + 37748736);    //  2,097,152
  u16*      fused  = (u16*)     (ws + 56623104);    //  4,194,304
  u16*      P      = (u16*)     (ws + 60817408);    //  4,460,544 (padded NHWC)
  float*    hbuf   = (float*)   (ws + 65277952);    //  4,194,304
  float*    gamma  = (float*)   (ws + 82055168);
  float*    beta   = (float*)   (ws + 82057216);
  float*    q      = (float*)   (ws + 82059264);
  float*    u      = (float*)   (ws + 82092032);
  float*    v      = (float*)   (ws + 82124800);
  u16*      Wo_bf  = (u16*)     (ws + 82157568);    //    131,072
  u16*      Wc1r   = (u16*)     (ws + 82288640);    //    589,824
  float*    pSum   = (float*)   (ws + 82878464);
  float*    pSsq   = (float*)   (ws + 82911232);
  u8*       flags  = (u8*)      (ws + 82944000);    //      2,048

  float* outp = (float*)d_out;                 // [2,256,64,64]
  float* hm   = outp + 2*C_*N_;                // [2,2,64,64]

  k_prep  <<<309, 1024, 0, stream>>>(txt, Wt, bt, Wg, bg, Wb, bb, dens, Wo, Wc1,
                                     gamma, beta, q, u, Wo_bf, Wc1r, P);
  k_build <<<dim3(64,2), 256, 0, stream>>>(img, gamma, beta, Sn);
  k_simK  <<<dim3(528,1,2), 256, 0, stream>>>(Sn, K8, flags);
  k_sink  <<<dim3(32,2), 256, 0, stream>>>(K8, flags, q, img, gamma, beta, u, v, uS8);
  k_fused <<<dim3(2,32,2), 256, 0, stream>>>(K8, uS8, flags, v, fused);
  k_outproj<<<dim3(32,4,2), 256, 0, stream>>>(fused, Wo_bf, img, bo, outp, P);
  k_conv  <<<dim3(32,2), 256, 0, stream>>>(P, Wc1r, bc1, hbuf, pSum, pSsq);
  k_head  <<<32, 256, 0, stream>>>(hbuf, pSum, pSsq, bng, bnb, Wc2, bc2, hm);
}

// Round 12
// 137.544 us; speedup vs baseline: 1.1653x; 1.1653x over previous
//
#include <hip/hip_runtime.h>
#include <stdint.h>

#define B_   2
#define C_   256
#define N_   4096
#define TD_  512
#define OC_  128   // C/2
#define PW_  66    // padded width/height
#define PA_  4356  // 66*66

typedef float  f32x4  __attribute__((ext_vector_type(4)));
typedef short  bf16x8 __attribute__((ext_vector_type(8)));
typedef unsigned short u16;
typedef unsigned char  u8;

__device__ __forceinline__ u16 f2bf(float x){
  union { float f; uint32_t u; } v; v.f = x;
  uint32_t r = v.u + 0x7fffu + ((v.u >> 16) & 1u);
  return (u16)(r >> 16);
}
// f32 -> e5m2 byte (clamped, RNE via f16 high-byte truncation)
__device__ __forceinline__ uint32_t f2e5m2(float x){
  x = fminf(fmaxf(x, -57344.f), 57344.f);
  union { _Float16 h; u16 u; } c; c.h = (_Float16)x;
  uint32_t hb = c.u;
  return ((hb + 0x7fu + ((hb >> 8) & 1u)) >> 8) & 0xffu;
}
__device__ __forceinline__ float e5m2f(uint32_t byte){
  union { u16 u; _Float16 h; } c; c.u = (u16)(byte << 8);
  return (float)c.h;
}

__device__ __forceinline__ void gld_lds16(const void* g, void* l){
  __builtin_amdgcn_global_load_lds(
      (const __attribute__((address_space(1))) unsigned int*)g,
      (__attribute__((address_space(3))) unsigned int*)l,
      16, 0, 0);
}

// ------- K1: prep (1024 thr/blk) = FiLM (0-1) + qinit (2-3) + repack (4..291) + Pzero (292..308)
__global__ __launch_bounds__(1024) void k_prep(
    const float* __restrict__ txt, const float* __restrict__ Wt, const float* __restrict__ bt,
    const float* __restrict__ Wg, const float* __restrict__ bg,
    const float* __restrict__ Wb, const float* __restrict__ bb,
    const float* __restrict__ dens, const float* __restrict__ Wo, const float* __restrict__ Wc1,
    float* __restrict__ gamma, float* __restrict__ beta,
    float* __restrict__ q, float* __restrict__ u,
    u16* __restrict__ Wo_bf, u16* __restrict__ Wc1r, u16* __restrict__ P){
  int bid = blockIdx.x;
  int t = threadIdx.x;
  if (bid < 2){                                   // ---- FiLM, 16-wave TLP, float4 loads
    int b = bid;
    __shared__ float ts[TD_];
    __shared__ float te[C_];
    if (t < TD_) ts[t] = txt[b*TD_ + t];
    __syncthreads();
    {
      int c = t >> 2, p = t & 3;                  // 4 threads per output
      const float4* w4 = (const float4*)(Wt + (size_t)c*TD_ + p*128);
      const float4* t4 = (const float4*)(ts + p*128);
      float a = 0.f;
      #pragma unroll 8
      for (int j = 0; j < 32; j++){
        float4 wv = w4[j], tv = t4[j];
        a += wv.x*tv.x + wv.y*tv.y + wv.z*tv.z + wv.w*tv.w;
      }
      a += __shfl_xor(a, 1);
      a += __shfl_xor(a, 2);
      if (p == 0) te[c] = a + bt[c];
    }
    __syncthreads();
    {
      int c = t >> 2, qb = (t >> 1) & 1, p = t & 1;   // (output, gamma/beta, half)
      const float* W = qb ? Wb : Wg;
      const float4* w4 = (const float4*)(W + (size_t)c*C_ + p*128);
      const float4* t4 = (const float4*)(te + p*128);
      float a = 0.f;
      #pragma unroll 8
      for (int j = 0; j < 32; j++){
        float4 wv = w4[j], tv = t4[j];
        a += wv.x*tv.x + wv.y*tv.y + wv.z*tv.z + wv.w*tv.w;
      }
      a += __shfl_xor(a, 1);
      if (p == 0){
        if (qb) beta[b*C_ + c]  = a + bb[c];
        else    gamma[b*C_ + c] = a + bg[c];
      }
    }
  } else if (bid < 4){                            // ---- qinit
    int b = bid - 2;
    __shared__ float red[1024];
    float s = 0.f;
    for (int i = t; i < N_; i += 1024){ float v = fmaxf(dens[b*N_ + i], 0.f) + 1e-6f; s += v; }
    red[t] = s; __syncthreads();
    for (int o = 512; o; o >>= 1){ if (t < o) red[t] += red[t + o]; __syncthreads(); }
    float invs = 1.f / red[0];
    for (int i = t; i < N_; i += 1024){
      float v = fmaxf(dens[b*N_ + i], 0.f) + 1e-6f;
      q[b*N_ + i] = v*invs;
      u[b*N_ + i] = 1.f;
    }
  } else if (bid < 292){                          // ---- repack (288 blocks x 1024 = 294912)
    int i = (bid - 4)*1024 + t;
    if (i < C_*C_) Wo_bf[i] = f2bf(Wo[i]);
    if (i < 9*OC_*C_){
      int s = i / (OC_*C_); int rem = i - s*(OC_*C_);
      int oc = rem >> 8; int ic = rem & 255;
      Wc1r[i] = f2bf(Wc1[((size_t)(oc*C_ + ic))*9 + s]);
    }
  } else {                                        // ---- P border zero (16640 uint4 total)
    int g = (bid - 292)*1024 + t;
    if (g < 16640){
      int px_i = g >> 5, seg = g & 31;
      int b = (px_i >= 260) ? 1 : 0;
      int i = px_i - b*260;
      int row, col;
      if (i < 66)      { row = 0;  col = i; }
      else if (i < 132){ row = 65; col = i - 66; }
      else { int i2 = i - 132; row = 1 + (i2 >> 1); col = (i2 & 1) ? 65 : 0; }
      uint4 z; z.x = 0; z.y = 0; z.z = 0; z.w = 0;
      *(uint4*)((char*)P + ((size_t)(b*PA_ + row*PW_ + col))*512 + seg*16) = z;
    }
  }
}

// ---------------------------------------- K2: mod + L2-normalize -> Sn NHWC bf16
__global__ __launch_bounds__(256) void k_build(
    const float* __restrict__ img, const float* __restrict__ gamma, const float* __restrict__ beta,
    u16* __restrict__ Sn){
  int b = blockIdx.y; int n0 = blockIdx.x*64;
  __shared__ float tile[C_][65];
  __shared__ float pss[4][64];
  __shared__ float inv[64];
  int t = threadIdx.x;
  int x = t & 63, cb = t >> 6;
  float ss = 0.f;
  for (int k = 0; k < 64; k++){
    int c = cb*64 + k;
    float v = img[((size_t)(b*C_ + c))*N_ + n0 + x];
    v = v*(1.f + gamma[b*C_ + c]) + beta[b*C_ + c];
    tile[c][x] = v;
    ss += v*v;
  }
  pss[cb][x] = ss;
  __syncthreads();
  if (t < 64){
    float s = pss[0][t] + pss[1][t] + pss[2][t] + pss[3][t];
    float nrm = sqrtf(s);
    inv[t] = 1.f / fmaxf(nrm, 1e-12f);
  }
  __syncthreads();
  for (int i = 0; i < 64; i++){
    int idx = i*256 + t;
    int c = idx & 255, nl = idx >> 8;
    Sn[((size_t)(b*N_ + n0 + nl))*C_ + c] = f2bf(tile[c][nl]*inv[nl]);
  }
}

// ------------------------- K3: sim = Sn@Sn^T (SYMMETRIC: upper-tri pairs only),
// K8 = e5m2(exp((sim-1)/eps)); per-tile nonzero FLAG. Zero tiles: flag only, NO stores
// (downstream reads are all flag-guarded, so zero tiles are never read).
__global__ __launch_bounds__(256) void k_simK(const u16* __restrict__ Sn, u8* __restrict__ K8,
                                              u8* __restrict__ flags){
  int idx = blockIdx.x;            // 0..527 upper-triangular pair index
  int b = blockIdx.z;
  int nt = (int)((sqrtf(8.f*idx + 1.f) - 1.f)*0.5f);
  while ((nt+1)*(nt+2)/2 <= idx) nt++;
  while (nt*(nt+1)/2 > idx) nt--;
  int mt = idx - nt*(nt+1)/2;      // mt <= nt
  __shared__ char smem[32768];     // As 16KB | Bs 16KB; epilogue reuses first 16KB
  __shared__ int fred[4];
  int t = threadIdx.x; int w = t >> 6; int l = t & 63;
  int wm = w >> 1, wn = w & 1;
  f32x4 acc[4][4] = {};
  const char* Ab = (const char*)(Sn + ((size_t)(b*N_ + mt*128))*C_);
  const char* Bb = (const char*)(Sn + ((size_t)(b*N_ + nt*128))*C_);
  for (int step = 0; step < 4; step++){
    __syncthreads();
    for (int r = 0; r < 4; r++){
      int off = r*4096 + t*16;
      int row = off >> 7;
      int col = (off & 127) ^ ((row & 7) << 4);   // inverse-swizzled source
      gld_lds16(Ab + (size_t)row*512 + step*128 + col, smem + off);
      gld_lds16(Bb + (size_t)row*512 + step*128 + col, smem + 16384 + off);
    }
    __syncthreads();
    for (int kk = 0; kk < 2; kk++){
      bf16x8 af[4], bfv[4];
      for (int i = 0; i < 4; i++){
        int ra = wm*64 + i*16 + (l & 15);
        af[i]  = *(const bf16x8*)(smem + ((ra*128 + kk*64 + (l>>4)*16) ^ ((ra & 7) << 4)));
        int rb = wn*64 + i*16 + (l & 15);
        bfv[i] = *(const bf16x8*)(smem + 16384 + ((rb*128 + kk*64 + (l>>4)*16) ^ ((rb & 7) << 4)));
      }
      for (int i = 0; i < 4; i++)
        for (int j = 0; j < 4; j++)
          acc[i][j] = __builtin_amdgcn_mfma_f32_16x16x32_bf16(af[i], bfv[j], acc[i][j], 0, 0, 0);
    }
  }
  // ---- tile nonzero flag (conservative: sim > 0.40 anywhere; e5m2 cutoff is 0.411)
  float tmax = -1.f;
  for (int i = 0; i < 4; i++)
    for (int j = 0; j < 4; j++){
      f32x4 a = acc[i][j];
      tmax = fmaxf(tmax, fmaxf(fmaxf(a[0], a[1]), fmaxf(a[2], a[3])));
    }
  int nz = __any(tmax > 0.40f) ? 1 : 0;
  if (l == 0) fred[w] = nz;
  __syncthreads();                 // also guarantees all MFMA LDS reads done
  int F = fred[0] | fred[1] | fred[2] | fred[3];
  if (t == 0){
    flags[b*1024 + nt*32 + mt] = (u8)F;
    if (mt != nt) flags[b*1024 + mt*32 + nt] = (u8)F;
  }
  if (!F) return;                  // zero tile: never read downstream (flag-guarded)
  size_t gb  = ((size_t)(b*N_ + nt*128))*N_ + mt*128;
  size_t gb2 = ((size_t)(b*N_ + mt*128))*N_ + nt*128;
  // epilogue 1: exp -> e5m2, tile[R=n][C=m] (swizzled), save packed words
  u8* tile = (u8*)smem;
  uint32_t wds[4][4];
  for (int i = 0; i < 4; i++)
    for (int j = 0; j < 4; j++){
      int R  = wn*64 + j*16 + (l & 15);          // n-side
      int Cc = wm*64 + i*16 + ((l >> 4) << 2);   // m-side (4 consecutive)
      uint32_t wd =  f2e5m2(__expf((acc[i][j][0] - 1.f)*20.f))
                  | (f2e5m2(__expf((acc[i][j][1] - 1.f)*20.f)) << 8)
                  | (f2e5m2(__expf((acc[i][j][2] - 1.f)*20.f)) << 16)
                  | (f2e5m2(__expf((acc[i][j][3] - 1.f)*20.f)) << 24);
      wds[i][j] = wd;
      *(uint32_t*)(tile + ((R*128 + Cc) ^ ((R & 7) << 4))) = wd;
    }
  __syncthreads();
  // write-out: K8[b][nt*128+R][mt*128 + 0..127]
  for (int p = 0; p < 4; p++){
    int id2 = p*256 + t;
    int R = id2 >> 3, sl = id2 & 7;
    uint4 vv = *(const uint4*)(tile + ((R*128 + sl*16) ^ ((R & 7) << 4)));
    *(uint4*)(K8 + gb + (size_t)R*N_ + sl*16) = vv;
  }
  // epilogue 2 (off-diagonal): transpose tile[R=m][C=n], write K8[mt-blk][nt-blk]
  if (mt != nt){
    __syncthreads();
    for (int i = 0; i < 4; i++)
      for (int j = 0; j < 4; j++){
        int m0 = wm*64 + i*16 + ((l >> 4) << 2);
        int n  = wn*64 + j*16 + (l & 15);
        uint32_t wd = wds[i][j];
        for (int r = 0; r < 4; r++){
          int R = m0 + r;
          tile[(R*128 + n) ^ ((R & 7) << 4)] = (u8)(wd >> (8*r));
        }
      }
    __syncthreads();
    for (int p = 0; p < 4; p++){
      int id2 = p*256 + t;
      int R = id2 >> 3, sl = id2 & 7;
      uint4 vv = *(const uint4*)(tile + ((R*128 + sl*16) ^ ((R & 7) << 4)));
      *(uint4*)(K8 + gb2 + (size_t)R*N_ + sl*16) = vv;
    }
  }
}

// ---- K4: Sinkhorn via flag-graph connected components, ONE launch.
// Owner (min tile in comp) runs all 3 iterations locally; per-pair flag guard
// (unflagged pairs are exact-zero tiles, never stored by simK).
__global__ __launch_bounds__(256) void k_sink(
    const u8* __restrict__ K8, const u8* __restrict__ flags,
    const float* __restrict__ q,
    const float* __restrict__ img, const float* __restrict__ gamma,
    const float* __restrict__ beta,
    float* __restrict__ u, float* __restrict__ v, u8* __restrict__ uS8){
  int r = blockIdx.x, b = blockIdx.y;
  int t = threadIdx.x;
  __shared__ uint32_t mask[32];
  __shared__ uint32_t comp_s;
  __shared__ u8 tl[32];
  __shared__ int scnt;
  __shared__ float xb[4096];
  __shared__ float yb[4096];
  if (t < 32){
    const u8* fr = flags + b*1024 + t*32;
    uint32_t m = 0;
    for (int j = 0; j < 32; j++) m |= (uint32_t)(fr[j] != 0) << j;
    mask[t] = m;
  }
  __syncthreads();
  if (t == 0){
    uint32_t comp = 1u << r;
    for (int it = 0; it < 32; it++){
      uint32_t nc = comp;
      for (int i = 0; i < 32; i++) if ((comp >> i) & 1u) nc |= mask[i];
      if (nc == comp) break;
      comp = nc;
    }
    comp_s = comp;
    int c = 0;
    for (int i = 0; i < 32; i++) if ((comp >> i) & 1u) tl[c++] = (u8)i;
    scnt = c;
  }
  __syncthreads();
  uint32_t comp = comp_s;
  if (comp & ((1u << r) - 1u)) return;   // block-uniform: not the owner
  int s = scnt;
  int R = s*128;
  for (int i = t; i < R; i += 256) xb[i] = 1.f;   // u0 = 1
  __syncthreads();
  for (int it = 0; it < 6; it++){
    int use_q = !(it & 1);
    for (int ri = t; ri < R; ri += 256){
      int rt = tl[ri >> 7];
      int gm = rt*128 + (ri & 127);
      const u8* kp = K8 + ((size_t)(b*N_ + gm))*N_;
      uint32_t rowmask = mask[rt];
      float ssum = 0.f;
      for (int ci = 0; ci < s; ci++){
        if (!((rowmask >> tl[ci]) & 1u)) continue;  // exact-zero tile, never stored
        const u8* kt = kp + tl[ci]*128;
        const float* xp = xb + ci*128;
        for (int kk = 0; kk < 16; kk++){
          uint2 kv = *(const uint2*)(kt + kk*8);
          const float* x8 = xp + kk*8;
          ssum += e5m2f( kv.x        & 0xff)*x8[0] + e5m2f((kv.x >>  8) & 0xff)*x8[1]
                + e5m2f((kv.x >> 16) & 0xff)*x8[2] + e5m2f( kv.x >> 24        )*x8[3];
          ssum += e5m2f( kv.y        & 0xff)*x8[4] + e5m2f((kv.y >>  8) & 0xff)*x8[5]
                + e5m2f((kv.y >> 16) & 0xff)*x8[6] + e5m2f( kv.y >> 24        )*x8[7];
        }
      }
      float marg = use_q ? q[b*N_ + gm] : 2.44140625e-4f;
      yb[ri] = marg / (ssum + 1e-8f);
    }
    __syncthreads();
    if (it == 4)
      for (int i = t; i < R; i += 256) v[b*N_ + tl[i >> 7]*128 + (i & 127)] = yb[i];
    if (it == 5)
      for (int i = t; i < R; i += 256) u[b*N_ + tl[i >> 7]*128 + (i & 127)] = yb[i];
    for (int i = t; i < R; i += 256) xb[i] = yb[i];
    __syncthreads();
  }
  // xb = final u for comp rows; emit uS8[b][c][n] for n in comp
  int qpc = R >> 2;                 // quads per channel
  int quads = C_ * qpc;
  for (int qd = t; qd < quads; qd += 256){
    int c  = qd / qpc;
    int nq = qd - c*qpc;
    int ri = nq*4;
    int n = tl[ri >> 7]*128 + (ri & 127);
    size_t bc = (size_t)(b*C_ + c);
    float gm = 1.f + gamma[bc];
    float bt = beta[bc];
    float4 vi = *(const float4*)(img + bc*N_ + n);
    uint32_t o =  f2e5m2((vi.x*gm + bt)*xb[ri+0])
               | (f2e5m2((vi.y*gm + bt)*xb[ri+1]) << 8)
               | (f2e5m2((vi.z*gm + bt)*xb[ri+2]) << 16)
               | (f2e5m2((vi.w*gm + bt)*xb[ri+3]) << 24);
    *(uint32_t*)(uS8 + bc*N_ + n) = o;
  }
}

// --------- K6: direct bf8xbf8 GEMM, full K (32 flag-guarded BK=128 steps), v-scaled bf16 out
__global__ __launch_bounds__(256) void k_fused(
    const u8* __restrict__ K8, const u8* __restrict__ uS8, const u8* __restrict__ flags,
    const float* __restrict__ vvec, u16* __restrict__ fused){
  int ct = blockIdx.x;              // 0..1 : 128-c block
  int mt = blockIdx.y, b = blockIdx.z;
  __shared__ char smem[32768];      // As [128c][128k] fp8 | Bs [128m][128k] fp8
  int t = threadIdx.x, w = t >> 6, l = t & 63;
  int wc = w >> 1, wm = w & 1;
  f32x4 acc[4][4] = {};
  const u8* Ab = uS8 + ((size_t)(b*C_ + ct*128))*N_;
  const u8* Bb = K8  + ((size_t)(b*N_ + mt*128))*N_;
  const u8* fr = flags + b*1024 + mt*32;
  for (int step = 0; step < 32; step++){
    if (!fr[step]) continue;        // all-zero K tile: exact skip (block-uniform)
    __syncthreads();
    for (int r = 0; r < 4; r++){
      int off = r*4096 + t*16;
      int row = off >> 7;
      int col = (off & 127) ^ ((row & 7) << 4);
      gld_lds16(Ab + (size_t)row*N_ + step*128 + col, smem + off);
      gld_lds16(Bb + (size_t)row*N_ + step*128 + col, smem + 16384 + off);
    }
    __syncthreads();
    for (int kk = 0; kk < 4; kk++){
      long av[4], bv[4];
      for (int i = 0; i < 4; i++){
        int ra = wc*64 + i*16 + (l & 15);
        av[i] = *(const long*)(smem + ((ra*128 + kk*32 + (l>>4)*8) ^ ((ra & 7) << 4)));
        int rb = wm*64 + i*16 + (l & 15);
        bv[i] = *(const long*)(smem + 16384 + ((rb*128 + kk*32 + (l>>4)*8) ^ ((rb & 7) << 4)));
      }
      for (int i = 0; i < 4; i++)
        for (int j = 0; j < 4; j++)
          acc[i][j] = __builtin_amdgcn_mfma_f32_16x16x32_bf8_bf8(av[i], bv[j], acc[i][j], 0, 0, 0);
    }
  }
  for (int j = 0; j < 4; j++){
    int m = mt*128 + wm*64 + j*16 + (l & 15);
    float vm = vvec[b*N_ + m];
    for (int i = 0; i < 4; i++){
      int c0 = ct*128 + wc*64 + i*16 + ((l >> 4) << 2);
      ushort4 o;
      o.x = f2bf(acc[i][j][0]*vm);
      o.y = f2bf(acc[i][j][1]*vm);
      o.z = f2bf(acc[i][j][2]*vm);
      o.w = f2bf(acc[i][j][3]*vm);
      *(ushort4*)(fused + ((size_t)(b*N_ + m))*C_ + c0) = o;
    }
  }
}

// -------- K7: out = img + Wo@fused + bo (NCHW f32) AND padded-NHWC bf16 P (LDS transpose)
__global__ __launch_bounds__(256) void k_outproj(
    const u16* __restrict__ fused, const u16* __restrict__ Wo_bf,
    const float* __restrict__ img, const float* __restrict__ bo,
    float* __restrict__ out, u16* __restrict__ P){
  int nt = blockIdx.x, ot = blockIdx.y, b = blockIdx.z;
  int t = threadIdx.x, w = t >> 6, l = t & 63;
  int wm = w >> 1, wn = w & 1;
  __shared__ u16 tile[128][72];   // [n_local][o_local], pad 72
  f32x4 acc[4][2] = {};
  for (int kc = 0; kc < 8; kc++){
    bf16x8 af[4], bfv[2];
    for (int i = 0; i < 4; i++){
      int n = nt*128 + wm*64 + i*16 + (l & 15);
      af[i] = *(const bf16x8*)(fused + ((size_t)(b*N_ + n))*C_ + kc*32 + (l >> 4)*8);
    }
    for (int j = 0; j < 2; j++){
      int o = ot*64 + wn*32 + j*16 + (l & 15);
      bfv[j] = *(const bf16x8*)(Wo_bf + (size_t)o*C_ + kc*32 + (l >> 4)*8);
    }
    for (int i = 0; i < 4; i++)
      for (int j = 0; j < 2; j++)
        acc[i][j] = __builtin_amdgcn_mfma_f32_16x16x32_bf16(af[i], bfv[j], acc[i][j], 0, 0, 0);
  }
  for (int i = 0; i < 4; i++)
    for (int j = 0; j < 2; j++){
      int ol = wn*32 + j*16 + (l & 15);
      int o = ot*64 + ol;
      int nl = wm*64 + i*16 + ((l >> 4) << 2);
      int n = nt*128 + nl;
      size_t a = ((size_t)(b*C_ + o))*N_ + n;
      float4 iv = *(const float4*)(img + a);
      float bov = bo[o];
      float4 r;
      r.x = iv.x + acc[i][j][0] + bov;
      r.y = iv.y + acc[i][j][1] + bov;
      r.z = iv.z + acc[i][j][2] + bov;
      r.w = iv.w + acc[i][j][3] + bov;
      *(float4*)(out + a) = r;
      tile[nl+0][ol] = f2bf(r.x);
      tile[nl+1][ol] = f2bf(r.y);
      tile[nl+2][ol] = f2bf(r.z);
      tile[nl+3][ol] = f2bf(r.w);
    }
  __syncthreads();
  for (int p = 0; p < 4; p++){
    int idx = p*256 + t;
    int row = idx >> 3, seg = idx & 7;
    int n = nt*128 + row;
    int y = n >> 6, x = n & 63;
    uint4 vv = *(const uint4*)(&tile[row][seg*8]);
    *(uint4*)(P + ((size_t)(b*PA_ + (y+1)*PW_ + (x+1)))*C_ + ot*64 + seg*8) = vv;
  }
}

// ---------------- K8: conv3x3 via padded-GEMM, tile 128px x 128oc, K=768 (3dx x 256ch),
// split over 3 dy-groups -> f32 partials. simK-style staging/swizzle. (R10-verified)
__global__ __launch_bounds__(256) void k_conv(
    const u16* __restrict__ P, const u16* __restrict__ Wc1r, float* __restrict__ convP){
  int pt = blockIdx.x;            // 0..31 : 128 px (2 image rows)
  int sp = blockIdx.y;            // 0..2  : dy group
  int b  = blockIdx.z;
  int dy = sp - 1;
  __shared__ char smem[32768];    // As(weights) 16KB | Bs(pixels) 16KB
  int t = threadIdx.x, w = t >> 6, l = t & 63;
  int wm = w >> 1, wn = w & 1;
  f32x4 acc[4][4] = {};
  int y0 = pt*2;
  size_t prow[4], wrow[4];
  int colsw[4];
  #pragma unroll
  for (int rr = 0; rr < 4; rr++){
    int off = rr*4096 + t*16;
    int row = off >> 7;
    int col = (off & 127) ^ ((row & 7) << 4);
    colsw[rr] = col;
    int gy = row >> 6, gx = row & 63;
    prow[rr] = ((size_t)(b*PA_ + (y0 + gy + dy + 1)*PW_ + gx + 1))*512;
    wrow[rr] = ((size_t)(sp*3*128 + row))*512;
  }
  const char* Pb = (const char*)P;
  const char* Wb = (const char*)Wc1r;
  for (int step = 0; step < 12; step++){
    int dxi = step >> 2, c64 = step & 3;          // dx = dxi-1, 64-ch chunk
    __syncthreads();
    #pragma unroll
    for (int rr = 0; rr < 4; rr++){
      int off = rr*4096 + t*16;
      gld_lds16(Wb + wrow[rr] + (size_t)dxi*65536 + c64*128 + colsw[rr], smem + off);
      gld_lds16(Pb + prow[rr] + (dxi-1)*512 + c64*128 + colsw[rr], smem + 16384 + off);
    }
    __syncthreads();
    for (int kk = 0; kk < 2; kk++){
      bf16x8 af[4], bv[4];
      for (int i = 0; i < 4; i++){
        int ra = wm*64 + i*16 + (l & 15);
        af[i] = *(const bf16x8*)(smem + ((ra*128 + kk*64 + (l>>4)*16) ^ ((ra & 7) << 4)));
        int rb = wn*64 + i*16 + (l & 15);
        bv[i] = *(const bf16x8*)(smem + 16384 + ((rb*128 + kk*64 + (l>>4)*16) ^ ((rb & 7) << 4)));
      }
      for (int i = 0; i < 4; i++)
        for (int j = 0; j < 4; j++)
          acc[i][j] = __builtin_amdgcn_mfma_f32_16x16x32_bf16(af[i], bv[j], acc[i][j], 0, 0, 0);
    }
  }
  float* pp = convP + (((size_t)(sp*2 + b))*N_ + (size_t)pt*128)*OC_;
  for (int i = 0; i < 4; i++)
    for (int j = 0; j < 4; j++){
      int pxl = wn*64 + j*16 + (l & 15);
      int ocl = wm*64 + i*16 + ((l >> 4) << 2);
      float4 r; r.x = acc[i][j][0]; r.y = acc[i][j][1]; r.z = acc[i][j][2]; r.w = acc[i][j][3];
      *(float4*)(pp + (size_t)pxl*OC_ + ocl) = r;
    }
}

// ------------- K9a: fold 3 conv partials + bias -> h (f32) + BN partial sums (R10-verified)
__global__ __launch_bounds__(256) void k_stats(
    const float* __restrict__ convP, const float* __restrict__ bc1,
    float* __restrict__ h, float* __restrict__ pSum, float* __restrict__ pSsq){
  int blk = blockIdx.x;     // 64 blocks x 128 rows (R = b*4096+px)
  int t = threadIdx.x; int c = t & 127, half = t >> 7;
  __shared__ float s1[256], s2[256];
  float bias = bc1[c];
  float a = 0.f, b2 = 0.f;
  int R0 = blk*128 + half*64;
  for (int r = 0; r < 64; r++){
    size_t base = (size_t)(R0 + r)*OC_ + c;
    float v = convP[base] + convP[base + (size_t)8192*OC_] + convP[base + (size_t)16384*OC_] + bias;
    h[base] = v;
    a += v; b2 += v*v;
  }
  s1[t] = a; s2[t] = b2;
  __syncthreads();
  if (t < 128){
    pSum[blk*128 + c] = s1[t] + s1[t + 128];
    pSsq[blk*128 + c] = s2[t] + s2[t + 128];
  }
}

// ----------- K10: BN finalize (in-block) + relu(h*sc+sh) -> 1x1 conv (2ch) -> heatmap
__global__ __launch_bounds__(256) void k_head(
    const float* __restrict__ h, const float* __restrict__ pSum, const float* __restrict__ pSsq,
    const float* __restrict__ bn_g, const float* __restrict__ bn_b,
    const float* __restrict__ Wc2, const float* __restrict__ bc2, float* __restrict__ hm){
  __shared__ float sc[128], sh[128], w0[128], w1[128];
  __shared__ float rs[256], rss[256];
  int t = threadIdx.x;
  {
    int c = t & 127, half = t >> 7;
    float s = 0.f, ss = 0.f;
    for (int k = half*32; k < half*32 + 32; k++){
      s += pSum[k*128 + c]; ss += pSsq[k*128 + c];
    }
    rs[t] = s; rss[t] = ss;
  }
  __syncthreads();
  if (t < 128){
    float s = rs[t] + rs[t+128], ss = rss[t] + rss[t+128];
    float m = s*(1.f/8192.f);
    float var = ss*(1.f/8192.f) - m*m;
    float scv = bn_g[t]*rsqrtf(var + 1e-5f);
    sc[t] = scv; sh[t] = bn_b[t] - m*scv;
    w0[t] = Wc2[t]; w1[t] = Wc2[128 + t];
  }
  __syncthreads();
  int n = blockIdx.x*256 + t;          // 0..8191 = b*4096+p
  const float* hp = h + (size_t)n*OC_;
  float a0 = bc2[0], a1 = bc2[1];
  for (int c4 = 0; c4 < 32; c4++){
    float4 hv = *(const float4*)(hp + c4*4);
    int c = c4*4;
    float r;
    r = fmaxf(hv.x*sc[c]   + sh[c],   0.f); a0 += w0[c]*r;   a1 += w1[c]*r;
    r = fmaxf(hv.y*sc[c+1] + sh[c+1], 0.f); a0 += w0[c+1]*r; a1 += w1[c+1]*r;
    r = fmaxf(hv.z*sc[c+2] + sh[c+2], 0.f); a0 += w0[c+2]*r; a1 += w1[c+2]*r;
    r = fmaxf(hv.w*sc[c+3] + sh[c+3], 0.f); a0 += w0[c+3]*r; a1 += w1[c+3]*r;
  }
  int b = n >> 12, p = n & 4095;
  hm[((size_t)(b*2 + 0))*N_ + p] = a0;
  hm[((size_t)(b*2 + 1))*N_ + p] = a1;
}

// ================================================================ launcher
extern "C" void kernel_launch(void* const* d_in, const int* in_sizes, int n_in,
                              void* d_out, int out_size, void* d_ws, size_t ws_size,
                              hipStream_t stream){
  const float* img  = (const float*)d_in[0];
  const float* txt  = (const float*)d_in[1];
  const float* dens = (const float*)d_in[2];
  const float* Wt   = (const float*)d_in[3];
  const float* bt   = (const float*)d_in[4];
  const float* Wg   = (const float*)d_in[5];
  const float* bg   = (const float*)d_in[6];
  const float* Wb   = (const float*)d_in[7];
  const float* bb   = (const float*)d_in[8];
  const float* Wo   = (const float*)d_in[9];
  const float* bo   = (const float*)d_in[10];
  const float* Wc1  = (const float*)d_in[11];
  const float* bc1  = (const float*)d_in[12];
  const float* bng  = (const float*)d_in[13];
  const float* bnb  = (const float*)d_in[14];
  const float* Wc2  = (const float*)d_in[15];
  const float* bc2  = (const float*)d_in[16];

  char* ws = (char*)d_ws;
  u8*       K8     = (u8*)      (ws + 0);           // 33,554,432
  u16*      Sn     = (u16*)     (ws + 33554432);    //  4,194,304
  u8*       uS8    = (u8*)      (ws + 37748736);    //  2,097,152
  u16*      fused  = (u16*)     (ws + 56623104);    //  4,194,304
  u16*      P      = (u16*)     (ws + 60817408);    //  4,460,544 (padded NHWC)
  float*    hbuf   = (float*)   (ws + 65277952);    //  4,194,304
  float*    convP  = (float*)   (ws + 69472256);    // 12,582,912
  float*    gamma  = (float*)   (ws + 82055168);
  float*    beta   = (float*)   (ws + 82057216);
  float*    q      = (float*)   (ws + 82059264);
  float*    u      = (float*)   (ws + 82092032);
  float*    v      = (float*)   (ws + 82124800);
  u16*      Wo_bf  = (u16*)     (ws + 82157568);    //    131,072
  u16*      Wc1r   = (u16*)     (ws + 82288640);    //    589,824
  float*    pSum   = (float*)   (ws + 82878464);
  float*    pSsq   = (float*)   (ws + 82911232);
  u8*       flags  = (u8*)      (ws + 82944000);    //      2,048

  float* outp = (float*)d_out;                 // [2,256,64,64]
  float* hm   = outp + 2*C_*N_;                // [2,2,64,64]

  k_prep  <<<309, 1024, 0, stream>>>(txt, Wt, bt, Wg, bg, Wb, bb, dens, Wo, Wc1,
                                     gamma, beta, q, u, Wo_bf, Wc1r, P);
  k_build <<<dim3(64,2), 256, 0, stream>>>(img, gamma, beta, Sn);
  k_simK  <<<dim3(528,1,2), 256, 0, stream>>>(Sn, K8, flags);
  k_sink  <<<dim3(32,2), 256, 0, stream>>>(K8, flags, q, img, gamma, beta, u, v, uS8);
  k_fused <<<dim3(2,32,2), 256, 0, stream>>>(K8, uS8, flags, v, fused);
  k_outproj<<<dim3(32,4,2), 256, 0, stream>>>(fused, Wo_bf, img, bo, outp, P);
  k_conv  <<<dim3(32,3,2), 256, 0, stream>>>(P, Wc1r, convP);
  k_stats <<<64, 256, 0, stream>>>(convP, bc1, hbuf, pSum, pSsq);
  k_head  <<<32, 256, 0, stream>>>(hbuf, pSum, pSsq, bng, bnb, Wc2, bc2, hm);
}